// Round 15
// baseline (94.564 us; speedup 1.0000x reference)
//
#include <hip/hip_runtime.h>

#define HDIM    256
#define HHALF   128
#define NTYPE   100
#define GPC     4      // crystals per block: 2 groups x 2
#define S       260    // LDS h-row stride
#define THREADS 256
#define SLOT    18     // partial slot stride (floats)
#define REGN    (32 * SLOT)

typedef float f32x4_n __attribute__((ext_vector_type(4)));

__device__ __forceinline__ float silu_f(float x) {
    return x / (1.0f + __expf(-x));
}

#define LD4(p) (*(const float4*)(p))
#define FMA4(A, s, v) do { (A).x += (s)*(v).x; (A).y += (s)*(v).y; \
                           (A).z += (s)*(v).z; (A).w += (s)*(v).w; } while (0)

// 2 rows x 8 cols (lo j0, hi j0+128), KT k-rows, ldw = HDIM
template<int KT>
__device__ __forceinline__ void gemm_2x8(
    const float* hb, const float* __restrict__ W, float4* acc)
{
    float4 h0 = LD4(hb), h1 = LD4(hb + S);
#pragma unroll 1
    for (int k4 = 0; k4 < KT - 4; k4 += 4) {
        float4 n0 = LD4(hb + k4 + 4), n1 = LD4(hb + S + k4 + 4);
        const float* w = W + (size_t)k4 * HDIM;
        float4 w0l=LD4(w),        w0h=LD4(w+128);
        float4 w1l=LD4(w+HDIM),   w1h=LD4(w+HDIM+128);
        float4 w2l=LD4(w+2*HDIM), w2h=LD4(w+2*HDIM+128);
        float4 w3l=LD4(w+3*HDIM), w3h=LD4(w+3*HDIM+128);
        FMA4(acc[0],h0.x,w0l); FMA4(acc[1],h0.x,w0h);
        FMA4(acc[0],h0.y,w1l); FMA4(acc[1],h0.y,w1h);
        FMA4(acc[0],h0.z,w2l); FMA4(acc[1],h0.z,w2h);
        FMA4(acc[0],h0.w,w3l); FMA4(acc[1],h0.w,w3h);
        FMA4(acc[2],h1.x,w0l); FMA4(acc[3],h1.x,w0h);
        FMA4(acc[2],h1.y,w1l); FMA4(acc[3],h1.y,w1h);
        FMA4(acc[2],h1.z,w2l); FMA4(acc[3],h1.z,w2h);
        FMA4(acc[2],h1.w,w3l); FMA4(acc[3],h1.w,w3h);
        h0 = n0; h1 = n1;
    }
    {
        const float* w = W + (size_t)(KT - 4) * HDIM;
        float4 w0l=LD4(w),        w0h=LD4(w+128);
        float4 w1l=LD4(w+HDIM),   w1h=LD4(w+HDIM+128);
        float4 w2l=LD4(w+2*HDIM), w2h=LD4(w+2*HDIM+128);
        float4 w3l=LD4(w+3*HDIM), w3h=LD4(w+3*HDIM+128);
        FMA4(acc[0],h0.x,w0l); FMA4(acc[1],h0.x,w0h);
        FMA4(acc[0],h0.y,w1l); FMA4(acc[1],h0.y,w1h);
        FMA4(acc[0],h0.z,w2l); FMA4(acc[1],h0.z,w2h);
        FMA4(acc[0],h0.w,w3l); FMA4(acc[1],h0.w,w3h);
        FMA4(acc[2],h1.x,w0l); FMA4(acc[3],h1.x,w0h);
        FMA4(acc[2],h1.y,w1l); FMA4(acc[3],h1.y,w1h);
        FMA4(acc[2],h1.z,w2l); FMA4(acc[3],h1.z,w2h);
        FMA4(acc[2],h1.w,w3l); FMA4(acc[3],h1.w,w3h);
    }
}

// 2 rows x 4 cols, runtime ldw, KT k-rows
template<int KT>
__device__ __forceinline__ void gemm_2x4(
    const float* hb, const float* __restrict__ W, const int ldw, float4* a)
{
    float4 h0 = LD4(hb), h1 = LD4(hb + S);
#pragma unroll 1
    for (int k4 = 0; k4 < KT - 4; k4 += 4) {
        float4 n0 = LD4(hb + k4 + 4), n1 = LD4(hb + S + k4 + 4);
        const float* w = W + (size_t)k4 * ldw;
        float4 w0=LD4(w), w1=LD4(w+ldw), w2=LD4(w+2*ldw), w3=LD4(w+3*ldw);
        FMA4(a[0],h0.x,w0); FMA4(a[0],h0.y,w1); FMA4(a[0],h0.z,w2); FMA4(a[0],h0.w,w3);
        FMA4(a[1],h1.x,w0); FMA4(a[1],h1.y,w1); FMA4(a[1],h1.z,w2); FMA4(a[1],h1.w,w3);
        h0 = n0; h1 = n1;
    }
    {
        const float* w = W + (size_t)(KT - 4) * ldw;
        float4 w0=LD4(w), w1=LD4(w+ldw), w2=LD4(w+2*ldw), w3=LD4(w+3*ldw);
        FMA4(a[0],h0.x,w0); FMA4(a[0],h0.y,w1); FMA4(a[0],h0.z,w2); FMA4(a[0],h0.w,w3);
        FMA4(a[1],h1.x,w0); FMA4(a[1],h1.y,w1); FMA4(a[1],h1.z,w2); FMA4(a[1],h1.w,w3);
    }
}

__device__ __forceinline__ void shfl_reduce(float4* a, int n) {
#pragma unroll
    for (int i = 0; i < n; ++i) {
        a[i].x += __shfl_xor(a[i].x, 32);
        a[i].y += __shfl_xor(a[i].y, 32);
        a[i].z += __shfl_xor(a[i].z, 32);
        a[i].w += __shfl_xor(a[i].w, 32);
    }
}

// 2-group pipeline: P1 = compute g0 (256 thr); P2 = compute g1 (128 thr)
// || stream g0 (128 thr, 13 weighted stripes between top-level barriers);
// P3 = stream g1 (256 thr).
__global__ __launch_bounds__(THREADS, 4) void fused_kernel(
    const int* __restrict__ batch, int N,
    const float* __restrict__ t_emb,
    const float* __restrict__ w1a, const float* __restrict__ b1a,
    const float* __restrict__ w2a, const float* __restrict__ b2a,
    const float* __restrict__ wc1, const float* __restrict__ bc1,
    const float* __restrict__ wc2, const float* __restrict__ bc2,
    const float* __restrict__ wl1, const float* __restrict__ bl1,
    const float* __restrict__ wl2, const float* __restrict__ bl2,
    const float* __restrict__ wt,  const float* __restrict__ bt,
    float* __restrict__ out_coord,    // [N,3]
    float* __restrict__ cell_out,     // [B,6]
    f32x4_n* __restrict__ out_logits4)// [N,25] f4
{
    __shared__ float bufA[2 * S];
    __shared__ float bufB[2 * S];
    __shared__ float red[3 * REGN];      // 6.9 KB
    __shared__ float logits_s[2 * 208];  // [group][row*104]
    __shared__ float coord_s[2 * 8];     // [group][row*4]
    __shared__ int   lb_s[GPC + 1];
    __shared__ float cnt_s[GPC];

    const int tid = threadIdx.x;
    const int R0  = blockIdx.x * GPC;

    if (tid <= GPC) {
        int v = R0 + tid;
        int lo = 0, hi = N;
        while (lo < hi) { int mid = (lo + hi) >> 1; if (batch[mid] < v) lo = mid + 1; else hi = mid; }
        lb_s[tid] = lo;
    }
    if (tid < 128) {   // stage g0 rows (2 x 64 f4)
        const float4* src = (const float4*)(t_emb + (size_t)R0 * HDIM);
        int r = tid >> 6, kq = tid & 63;
        *(float4*)&bufA[r * S + kq * 4] = src[r * 64 + kq];
    }
    __syncthreads();
    if (tid < GPC) cnt_s[tid] = (float)(lb_s[tid + 1] - lb_s[tid]);

    const int cg = tid & 31, j0 = cg * 4;
    const int ksg8 = tid >> 5;      // phase1: 8 K-groups x 32
    const int wv   = tid >> 6;
    const bool lo_h = !(tid & 32);

    float4 acc[4];

    // ======= PHASE 1: group 0 (all 256 threads) =======
    // L1
#pragma unroll
    for (int i = 0; i < 4; ++i) acc[i] = make_float4(0.f,0.f,0.f,0.f);
    gemm_2x8<32>(&bufA[ksg8 * 32], w1a + (size_t)(ksg8 * 32) * HDIM + j0, acc);
    shfl_reduce(acc, 4);
    if (wv && lo_h) {
        float* rp = &red[(wv - 1) * REGN + cg * SLOT];
        *(float4*)rp = acc[0]; *(float4*)(rp+4) = acc[1];
        *(float4*)(rp+8) = acc[2]; *(float4*)(rp+12) = acc[3];
    }
    __syncthreads();
    if (tid < 32) {
#pragma unroll
        for (int p = 0; p < 3; ++p) {
            const float* rp = &red[p * REGN + tid * SLOT];
            float4 p0=LD4(rp), p1=LD4(rp+4), p2=LD4(rp+8), p3=LD4(rp+12);
            FMA4(acc[0],1.f,p0); FMA4(acc[1],1.f,p1); FMA4(acc[2],1.f,p2); FMA4(acc[3],1.f,p3);
        }
        float4 bl = LD4(b1a + j0), bh = LD4(b1a + j0 + 128);
#pragma unroll
        for (int r = 0; r < 2; ++r) {
            float4 vl, vh;
            vl.x=silu_f(acc[2*r].x+bl.x); vl.y=silu_f(acc[2*r].y+bl.y);
            vl.z=silu_f(acc[2*r].z+bl.z); vl.w=silu_f(acc[2*r].w+bl.w);
            vh.x=silu_f(acc[2*r+1].x+bh.x); vh.y=silu_f(acc[2*r+1].y+bh.y);
            vh.z=silu_f(acc[2*r+1].z+bh.z); vh.w=silu_f(acc[2*r+1].w+bh.w);
            *(float4*)&bufB[r * S + j0] = vl;
            *(float4*)&bufB[r * S + j0 + 128] = vh;
        }
    }
    __syncthreads();
    // L2
#pragma unroll
    for (int i = 0; i < 4; ++i) acc[i] = make_float4(0.f,0.f,0.f,0.f);
    gemm_2x8<32>(&bufB[ksg8 * 32], w2a + (size_t)(ksg8 * 32) * HDIM + j0, acc);
    shfl_reduce(acc, 4);
    if (wv && lo_h) {
        float* rp = &red[(wv - 1) * REGN + cg * SLOT];
        *(float4*)rp = acc[0]; *(float4*)(rp+4) = acc[1];
        *(float4*)(rp+8) = acc[2]; *(float4*)(rp+12) = acc[3];
    }
    __syncthreads();
    if (tid < 32) {
#pragma unroll
        for (int p = 0; p < 3; ++p) {
            const float* rp = &red[p * REGN + tid * SLOT];
            float4 p0=LD4(rp), p1=LD4(rp+4), p2=LD4(rp+8), p3=LD4(rp+12);
            FMA4(acc[0],1.f,p0); FMA4(acc[1],1.f,p1); FMA4(acc[2],1.f,p2); FMA4(acc[3],1.f,p3);
        }
        float4 bl = LD4(b2a + j0), bh = LD4(b2a + j0 + 128);
#pragma unroll
        for (int r = 0; r < 2; ++r) {
            float4 vl, vh;
            vl.x=acc[2*r].x+bl.x; vl.y=acc[2*r].y+bl.y; vl.z=acc[2*r].z+bl.z; vl.w=acc[2*r].w+bl.w;
            vh.x=acc[2*r+1].x+bh.x; vh.y=acc[2*r+1].y+bh.y; vh.z=acc[2*r+1].z+bh.z; vh.w=acc[2*r+1].w+bh.w;
            *(float4*)&bufA[r * S + j0] = vl;
            *(float4*)&bufA[r * S + j0 + 128] = vh;
        }
    }
    __syncthreads();
    // logits g0
    {
        float4 a2[2];
        a2[0] = make_float4(0.f,0.f,0.f,0.f); a2[1] = a2[0];
        if (cg < 25)
            gemm_2x4<32>(&bufA[ksg8 * 32], wt + (size_t)(ksg8 * 32) * NTYPE + j0, NTYPE, a2);
        shfl_reduce(a2, 2);
        if (wv && lo_h && cg < 25) {
            float* rp = &red[(wv - 1) * REGN + cg * SLOT];
            *(float4*)rp = a2[0]; *(float4*)(rp+4) = a2[1];
        }
        __syncthreads();
        if (tid < 25) {
#pragma unroll
            for (int p = 0; p < 3; ++p) {
                const float* rp = &red[p * REGN + tid * SLOT];
                float4 p0=LD4(rp), p1=LD4(rp+4);
                FMA4(a2[0],1.f,p0); FMA4(a2[1],1.f,p1);
            }
            float4 b4 = LD4(bt + j0);
            *(float4*)&logits_s[j0]       = make_float4(a2[0].x+b4.x,a2[0].y+b4.y,a2[0].z+b4.z,a2[0].w+b4.w);
            *(float4*)&logits_s[104 + j0] = make_float4(a2[1].x+b4.x,a2[1].y+b4.y,a2[1].z+b4.z,a2[1].w+b4.w);
        }
        __syncthreads();
    }
    // heads g0: tid<128 coord, tid>=128 cell; 4 hks x 64k
    {
        const bool ic  = (tid >= 128);
        const int  t7  = tid & 127;
        const int  hcg = t7 & 31, hj0 = hcg * 4;
        const int  hks = t7 >> 5;
        const float* W  = ic ? wl1 : wc1;
        const float* bb = ic ? bl1 : bc1;
        float4 ha[2];
        ha[0] = make_float4(0.f,0.f,0.f,0.f); ha[1] = ha[0];
        gemm_2x4<64>(&bufA[hks * 64], W + (size_t)(hks * 64) * HHALF + hj0, HHALF, ha);
        shfl_reduce(ha, 2);
        if ((t7 >= 64) && !(t7 & 32)) {
            float* rp = &red[(ic ? REGN : 0) + hcg * SLOT];
            *(float4*)rp = ha[0]; *(float4*)(rp+4) = ha[1];
        }
        __syncthreads();
        if (t7 < 32) {
            const float* rp = &red[(ic ? REGN : 0) + hcg * SLOT];
            float4 p0=LD4(rp), p1=LD4(rp+4);
            FMA4(ha[0],1.f,p0); FMA4(ha[1],1.f,p1);
            float4 b4 = LD4(bb + hj0);
            const int off = ic ? HHALF : 0;
#pragma unroll
            for (int r = 0; r < 2; ++r) {
                const float sc = ic ? cnt_s[r] : 1.f;
                float4 v;
                v.x=silu_f(ha[r].x*sc+b4.x); v.y=silu_f(ha[r].y*sc+b4.y);
                v.z=silu_f(ha[r].z*sc+b4.z); v.w=silu_f(ha[r].w*sc+b4.w);
                *(float4*)&bufB[r * S + off + hj0] = v;
            }
        }
    }
    __syncthreads();
    // tiny g0
    if (tid < 6) {
        int r = tid / 3, c = tid - 3 * r;
        float a = 0.f;
#pragma unroll 4
        for (int k = 0; k < HHALF; k += 4) {
            float4 hv = LD4(&bufB[r * S + k]);
            a += hv.x*wc2[k*3+c] + hv.y*wc2[(k+1)*3+c] + hv.z*wc2[(k+2)*3+c] + hv.w*wc2[(k+3)*3+c];
        }
        coord_s[r * 4 + c] = a + bc2[c];
    } else if (tid >= 64 && tid < 76) {
        int t2 = tid - 64;
        int r = t2 / 6, c = t2 - 6 * r;
        float a = 0.f;
#pragma unroll 4
        for (int k = 0; k < HHALF; k += 4) {
            float4 hv = LD4(&bufB[r * S + HHALF + k]);
            a += hv.x*wl2[k*6+c] + hv.y*wl2[(k+1)*6+c] + hv.z*wl2[(k+2)*6+c] + hv.w*wl2[(k+3)*6+c];
        }
        cell_out[(size_t)(R0 + r) * 6 + c] = a + bl2[c];
    }
    __syncthreads();

    // ======= PHASE 2: compute g1 (tid<128) || stream g0 (tid>=128) =======
    const int lb0 = lb_s[0], lb1 = lb_s[1], lb2 = lb_s[2], lb3 = lb_s[3], lb4 = lb_s[4];
    const int tot25_0 = (lb2 - lb0) * 25;
    const int CH = (tot25_0 + 12) / 13;   // 13 weighted stripes

#define SCH(s0, ns) do { \
    int tend = (s0 + ns) * CH; if (tend > tot25_0) tend = tot25_0; \
    for (int t = (tid - 128) + (s0) * CH; t < tend; t += 128) { \
        int a25 = t / 25; int q = t - 25 * a25; int atom = lb0 + a25; \
        int row = (atom >= lb1); \
        f32x4_n v = *(const f32x4_n*)&logits_s[row * 104 + q * 4]; \
        __builtin_nontemporal_store(v, &out_logits4[(size_t)atom * 25 + q]); \
    } } while (0)

    const int ksg4 = (tid >> 5) & 3;

    // A: stage g1 | stripe 0
    if (tid < 128) {
        const float4* src = (const float4*)(t_emb + (size_t)(R0 + 2) * HDIM);
        int r = tid >> 6, kq = tid & 63;
        *(float4*)&bufA[r * S + kq * 4] = src[r * 64 + kq];
    } else SCH(0, 1);
    __syncthreads();
    // B: L1 g1 | stripes 1-2
    if (tid < 128) {
#pragma unroll
        for (int i = 0; i < 4; ++i) acc[i] = make_float4(0.f,0.f,0.f,0.f);
        gemm_2x8<64>(&bufA[ksg4 * 64], w1a + (size_t)(ksg4 * 64) * HDIM + j0, acc);
        shfl_reduce(acc, 4);
        if (tid >= 64 && !(tid & 32)) {
            float* rp = &red[cg * SLOT];
            *(float4*)rp = acc[0]; *(float4*)(rp+4) = acc[1];
            *(float4*)(rp+8) = acc[2]; *(float4*)(rp+12) = acc[3];
        }
    } else SCH(1, 2);
    __syncthreads();
    // C: L1 fin | stripe 3
    if (tid < 32) {
        const float* rp = &red[tid * SLOT];
        float4 p0=LD4(rp), p1=LD4(rp+4), p2=LD4(rp+8), p3=LD4(rp+12);
        FMA4(acc[0],1.f,p0); FMA4(acc[1],1.f,p1); FMA4(acc[2],1.f,p2); FMA4(acc[3],1.f,p3);
        float4 bl = LD4(b1a + j0), bh = LD4(b1a + j0 + 128);
#pragma unroll
        for (int r = 0; r < 2; ++r) {
            float4 vl, vh;
            vl.x=silu_f(acc[2*r].x+bl.x); vl.y=silu_f(acc[2*r].y+bl.y);
            vl.z=silu_f(acc[2*r].z+bl.z); vl.w=silu_f(acc[2*r].w+bl.w);
            vh.x=silu_f(acc[2*r+1].x+bh.x); vh.y=silu_f(acc[2*r+1].y+bh.y);
            vh.z=silu_f(acc[2*r+1].z+bh.z); vh.w=silu_f(acc[2*r+1].w+bh.w);
            *(float4*)&bufB[r * S + j0] = vl;
            *(float4*)&bufB[r * S + j0 + 128] = vh;
        }
    } else if (tid >= 128) SCH(3, 1);
    __syncthreads();
    // D: L2 g1 | stripes 4-5
    if (tid < 128) {
#pragma unroll
        for (int i = 0; i < 4; ++i) acc[i] = make_float4(0.f,0.f,0.f,0.f);
        gemm_2x8<64>(&bufB[ksg4 * 64], w2a + (size_t)(ksg4 * 64) * HDIM + j0, acc);
        shfl_reduce(acc, 4);
        if (tid >= 64 && !(tid & 32)) {
            float* rp = &red[cg * SLOT];
            *(float4*)rp = acc[0]; *(float4*)(rp+4) = acc[1];
            *(float4*)(rp+8) = acc[2]; *(float4*)(rp+12) = acc[3];
        }
    } else SCH(4, 2);
    __syncthreads();
    // E: L2 fin | stripe 6
    if (tid < 32) {
        const float* rp = &red[tid * SLOT];
        float4 p0=LD4(rp), p1=LD4(rp+4), p2=LD4(rp+8), p3=LD4(rp+12);
        FMA4(acc[0],1.f,p0); FMA4(acc[1],1.f,p1); FMA4(acc[2],1.f,p2); FMA4(acc[3],1.f,p3);
        float4 bl = LD4(b2a + j0), bh = LD4(b2a + j0 + 128);
#pragma unroll
        for (int r = 0; r < 2; ++r) {
            float4 vl, vh;
            vl.x=acc[2*r].x+bl.x; vl.y=acc[2*r].y+bl.y; vl.z=acc[2*r].z+bl.z; vl.w=acc[2*r].w+bl.w;
            vh.x=acc[2*r+1].x+bh.x; vh.y=acc[2*r+1].y+bh.y; vh.z=acc[2*r+1].z+bh.z; vh.w=acc[2*r+1].w+bh.w;
            *(float4*)&bufA[r * S + j0] = vl;
            *(float4*)&bufA[r * S + j0 + 128] = vh;
        }
    } else if (tid >= 128) SCH(6, 1);
    __syncthreads();
    // F: logits g1 | stripes 7-8
    float4 a2[2];
    a2[0] = make_float4(0.f,0.f,0.f,0.f); a2[1] = a2[0];
    if (tid < 128) {
        if (cg < 25)
            gemm_2x4<64>(&bufA[ksg4 * 64], wt + (size_t)(ksg4 * 64) * NTYPE + j0, NTYPE, a2);
        shfl_reduce(a2, 2);
        if (tid >= 64 && !(tid & 32) && cg < 25) {
            float* rp = &red[cg * SLOT];
            *(float4*)rp = a2[0]; *(float4*)(rp+4) = a2[1];
        }
    } else SCH(7, 2);
    __syncthreads();
    // G: logits fin | stripe 9
    if (tid < 25) {
        const float* rp = &red[tid * SLOT];
        float4 p0=LD4(rp), p1=LD4(rp+4);
        FMA4(a2[0],1.f,p0); FMA4(a2[1],1.f,p1);
        float4 b4 = LD4(bt + j0);
        *(float4*)&logits_s[208 + j0]       = make_float4(a2[0].x+b4.x,a2[0].y+b4.y,a2[0].z+b4.z,a2[0].w+b4.w);
        *(float4*)&logits_s[208 + 104 + j0] = make_float4(a2[1].x+b4.x,a2[1].y+b4.y,a2[1].z+b4.z,a2[1].w+b4.w);
    } else if (tid >= 128) SCH(9, 1);
    __syncthreads();
    // H: heads g1 | stripes 10-11  (wave0 coord, wave1 cell; 2 hks x 128k)
    if (tid < 128) {
        const bool ic  = (tid >= 64);
        const int  hcg = tid & 31, hj0 = hcg * 4;
        const int  hks = (tid >> 5) & 1;
        const float* W  = ic ? wl1 : wc1;
        const float* bb = ic ? bl1 : bc1;
        float4 ha[2];
        ha[0] = make_float4(0.f,0.f,0.f,0.f); ha[1] = ha[0];
        gemm_2x4<128>(&bufA[hks * 128], W + (size_t)(hks * 128) * HHALF + hj0, HHALF, ha);
        shfl_reduce(ha, 2);
        if (!(tid & 32)) {
            float4 b4 = LD4(bb + hj0);
            const int off = ic ? HHALF : 0;
#pragma unroll
            for (int r = 0; r < 2; ++r) {
                const float sc = ic ? cnt_s[2 + r] : 1.f;
                float4 v;
                v.x=silu_f(ha[r].x*sc+b4.x); v.y=silu_f(ha[r].y*sc+b4.y);
                v.z=silu_f(ha[r].z*sc+b4.z); v.w=silu_f(ha[r].w*sc+b4.w);
                *(float4*)&bufB[r * S + off + hj0] = v;
            }
        }
    } else SCH(10, 2);
    __syncthreads();
    // I: tiny g1 | stripe 12 + g0 coord stream
    if (tid < 6) {
        int r = tid / 3, c = tid - 3 * r;
        float a = 0.f;
#pragma unroll 4
        for (int k = 0; k < HHALF; k += 4) {
            float4 hv = LD4(&bufB[r * S + k]);
            a += hv.x*wc2[k*3+c] + hv.y*wc2[(k+1)*3+c] + hv.z*wc2[(k+2)*3+c] + hv.w*wc2[(k+3)*3+c];
        }
        coord_s[8 + r * 4 + c] = a + bc2[c];
    } else if (tid >= 64 && tid < 76) {
        int t2 = tid - 64;
        int r = t2 / 6, c = t2 - 6 * r;
        float a = 0.f;
#pragma unroll 4
        for (int k = 0; k < HHALF; k += 4) {
            float4 hv = LD4(&bufB[r * S + HHALF + k]);
            a += hv.x*wl2[k*6+c] + hv.y*wl2[(k+1)*6+c] + hv.z*wl2[(k+2)*6+c] + hv.w*wl2[(k+3)*6+c];
        }
        cell_out[(size_t)(R0 + 2 + r) * 6 + c] = a + bl2[c];
    } else if (tid >= 128) {
        SCH(12, 1);
        const int tot3_0 = (lb2 - lb0) * 3;
        for (int t = tid - 128; t < tot3_0; t += 128) {
            int a3 = t / 3; int c = t - 3 * a3; int atom = lb0 + a3;
            int row = (atom >= lb1);
            __builtin_nontemporal_store(coord_s[row * 4 + c], &out_coord[(size_t)lb0 * 3 + t]);
        }
    }
    __syncthreads();

    // ======= PHASE 3: stream g1 (all 256) =======
    {
        const int tot25_1 = (lb4 - lb2) * 25;
        for (int t = tid; t < tot25_1; t += 256) {
            int a25 = t / 25; int q = t - 25 * a25; int atom = lb2 + a25;
            int row = (atom >= lb3);
            f32x4_n v = *(const f32x4_n*)&logits_s[208 + row * 104 + q * 4];
            __builtin_nontemporal_store(v, &out_logits4[(size_t)atom * 25 + q]);
        }
        const int tot3_1 = (lb4 - lb2) * 3;
        for (int t = tid; t < tot3_1; t += 256) {
            int a3 = t / 3; int c = t - 3 * a3; int atom = lb2 + a3;
            int row = (atom >= lb3);
            __builtin_nontemporal_store(coord_s[8 + row * 4 + c], &out_coord[(size_t)lb2 * 3 + t]);
        }
    }
#undef SCH
}

extern "C" void kernel_launch(void* const* d_in, const int* in_sizes, int n_in,
                              void* d_out, int out_size, void* d_ws, size_t ws_size,
                              hipStream_t stream)
{
    const int*   batch = (const int*)d_in[1];
    const float* t_emb = (const float*)d_in[3];
    const float* w1a = (const float*)d_in[4];
    const float* b1a = (const float*)d_in[5];
    const float* w2a = (const float*)d_in[6];
    const float* b2a = (const float*)d_in[7];
    const float* wc1 = (const float*)d_in[8];
    const float* bc1 = (const float*)d_in[9];
    const float* wc2 = (const float*)d_in[10];
    const float* bc2 = (const float*)d_in[11];
    const float* wl1 = (const float*)d_in[12];
    const float* bl1 = (const float*)d_in[13];
    const float* wl2 = (const float*)d_in[14];
    const float* bl2 = (const float*)d_in[15];
    const float* wt  = (const float*)d_in[16];
    const float* bt  = (const float*)d_in[17];

    const int N = in_sizes[1];        // 500000
    const int B = in_sizes[2] / 9;    // 4096

    float* out        = (float*)d_out;
    float* out_coord  = out;                                   // [N,3]
    float* cell_out   = out + (size_t)N * 3;                   // [B,6]
    float* out_logits = out + (size_t)N * 3 + (size_t)B * 6;   // [N,100]

    fused_kernel<<<B / GPC, THREADS, 0, stream>>>(
        batch, N, t_emb,
        w1a, b1a, w2a, b2a,
        wc1, bc1, wc2, bc2,
        wl1, bl1, wl2, bl2,
        wt, bt,
        out_coord, cell_out, (f32x4_n*)out_logits);
}

// Round 16
// 84.250 us; speedup vs baseline: 1.1224x; 1.1224x over previous
//
#include <hip/hip_runtime.h>

#define HDIM    256
#define HHALF   128
#define NTYPE   100
#define RPB     4      // crystals per block
#define SH2     132    // LDS h-row stride in half2 units (128 + 4 pad)
#define THREADS 256

typedef float f32x4_n __attribute__((ext_vector_type(4)));
typedef _Float16 h2_t __attribute__((ext_vector_type(2)));
union H2U { unsigned u; h2_t h; };

__device__ __forceinline__ float silu_f(float x) {
    return x / (1.0f + __expf(-x));
}

#define LD4(p) (*(const float4*)(p))

__device__ __forceinline__ float fdot2u(unsigned a, unsigned b, float c) {
    H2U x, y; x.u = a; y.u = b;
    return __builtin_amdgcn_fdot2(x.h, y.h, c, false);
}

// pack f32 weights into k-paired half2: out[k2*ld + j] = (w[2k2][j], w[2k2+1][j])
// layout in ws: w1h[128][256] | w2h[128][256] | wth[128][100] | wch[128][128] | wlh[128][128]
__global__ __launch_bounds__(256) void convert_kernel(
    const float* __restrict__ w1a, const float* __restrict__ w2a,
    const float* __restrict__ wt,  const float* __restrict__ wc1,
    const float* __restrict__ wl1, unsigned* __restrict__ outw)
{
    const int stride = gridDim.x * blockDim.x;
    for (int i = blockIdx.x * blockDim.x + threadIdx.x; i < 111104; i += stride) {
        const float* src; int k2, j, ld;
        if (i < 32768)      { src = w1a; ld = 256; k2 = i >> 8; j = i & 255; }
        else if (i < 65536) { src = w2a; ld = 256; int t = i - 32768; k2 = t >> 8; j = t & 255; }
        else if (i < 78336) { src = wt;  ld = 100; int t = i - 65536; k2 = t / 100; j = t - 100 * k2; }
        else if (i < 94720) { src = wc1; ld = 128; int t = i - 78336; k2 = t >> 7; j = t & 127; }
        else                { src = wl1; ld = 128; int t = i - 94720; k2 = t >> 7; j = t & 127; }
        H2U u;
        u.h = (h2_t){(_Float16)src[(size_t)(2 * k2) * ld + j],
                     (_Float16)src[(size_t)(2 * k2 + 1) * ld + j]};
        outw[i] = u.u;
    }
}

// 4 rows x 8 cols (lo j0, hi j0+128), 16 k2 (=32 k). dot2: 2 MACs/instr.
__device__ __forceinline__ void gemm_main_h(
    const unsigned* hb, const unsigned* __restrict__ W, float* acc)
{
    uint4 h[4];
#pragma unroll
    for (int r = 0; r < 4; ++r) h[r] = *(const uint4*)(hb + r * SH2);
#pragma unroll 1
    for (int ko = 0; ko < 4; ++ko) {
        uint4 hn[4];
        if (ko < 3) {
#pragma unroll
            for (int r = 0; r < 4; ++r) hn[r] = *(const uint4*)(hb + r * SH2 + (ko + 1) * 4);
        }
#pragma unroll
        for (int kk = 0; kk < 4; ++kk) {
            const unsigned* w = W + (size_t)(ko * 4 + kk) * 256;
            uint4 wl = *(const uint4*)w;
            uint4 wh = *(const uint4*)(w + 128);
#pragma unroll
            for (int r = 0; r < 4; ++r) {
                const unsigned hv = (kk == 0) ? h[r].x : (kk == 1) ? h[r].y
                                  : (kk == 2) ? h[r].z : h[r].w;
                acc[r*8+0] = fdot2u(hv, wl.x, acc[r*8+0]);
                acc[r*8+1] = fdot2u(hv, wl.y, acc[r*8+1]);
                acc[r*8+2] = fdot2u(hv, wl.z, acc[r*8+2]);
                acc[r*8+3] = fdot2u(hv, wl.w, acc[r*8+3]);
                acc[r*8+4] = fdot2u(hv, wh.x, acc[r*8+4]);
                acc[r*8+5] = fdot2u(hv, wh.y, acc[r*8+5]);
                acc[r*8+6] = fdot2u(hv, wh.z, acc[r*8+6]);
                acc[r*8+7] = fdot2u(hv, wh.w, acc[r*8+7]);
            }
        }
        if (ko < 3) {
#pragma unroll
            for (int r = 0; r < 4; ++r) h[r] = hn[r];
        }
    }
}

// 4 rows x 4 cols, NK2 k2-steps, runtime ld2 (in half2 units)
template<int NK2>
__device__ __forceinline__ void gemm_4x4h(
    const unsigned* hb, const unsigned* __restrict__ W, const int ld2, float* acc)
{
    uint4 h[4];
#pragma unroll
    for (int r = 0; r < 4; ++r) h[r] = *(const uint4*)(hb + r * SH2);
#pragma unroll 1
    for (int ko = 0; ko < NK2 / 4; ++ko) {
        uint4 hn[4];
        if (ko < NK2 / 4 - 1) {
#pragma unroll
            for (int r = 0; r < 4; ++r) hn[r] = *(const uint4*)(hb + r * SH2 + (ko + 1) * 4);
        }
#pragma unroll
        for (int kk = 0; kk < 4; ++kk) {
            const unsigned* w = W + (size_t)(ko * 4 + kk) * ld2;
            uint4 wv = *(const uint4*)w;
#pragma unroll
            for (int r = 0; r < 4; ++r) {
                const unsigned hv = (kk == 0) ? h[r].x : (kk == 1) ? h[r].y
                                  : (kk == 2) ? h[r].z : h[r].w;
                acc[r*4+0] = fdot2u(hv, wv.x, acc[r*4+0]);
                acc[r*4+1] = fdot2u(hv, wv.y, acc[r*4+1]);
                acc[r*4+2] = fdot2u(hv, wv.z, acc[r*4+2]);
                acc[r*4+3] = fdot2u(hv, wv.w, acc[r*4+3]);
            }
        }
        if (ko < NK2 / 4 - 1) {
#pragma unroll
            for (int r = 0; r < 4; ++r) h[r] = hn[r];
        }
    }
}

template<int NV>
__device__ __forceinline__ void shfl_red(float* a) {
#pragma unroll
    for (int i = 0; i < NV; ++i) a[i] += __shfl_xor(a[i], 32);
}

// R13 structure with f16-dot2 GEMMs. One block = 4 crystals.
__global__ __launch_bounds__(THREADS, 4) void fused_kernel(
    const int* __restrict__ batch, int N,
    const float* __restrict__ t_emb,
    const unsigned* __restrict__ wpk,   // packed weights (convert_kernel layout)
    const float* __restrict__ b1a, const float* __restrict__ b2a,
    const float* __restrict__ bc1, const float* __restrict__ bl1,
    const float* __restrict__ wc2, const float* __restrict__ bc2,
    const float* __restrict__ wl2, const float* __restrict__ bl2,
    const float* __restrict__ bt,
    float* __restrict__ out_coord,    // [N,3]
    float* __restrict__ cell_out,     // [B,6]
    f32x4_n* __restrict__ out_logits4)// [N,25] f4
{
    const unsigned* w1h = wpk;            // [128][256]
    const unsigned* w2h = wpk + 32768;    // [128][256]
    const unsigned* wth = wpk + 65536;    // [128][100]
    const unsigned* wch = wpk + 78336;    // [128][128]
    const unsigned* wlh = wpk + 94720;    // [128][128]

    __shared__ unsigned bufA[RPB * SH2];   // h0 / h as half2
    __shared__ unsigned bufB[RPB * SH2];   // h1 / gc,gl as half2
    __shared__ float red[3 * 1056];        // cross-wave partials (slot 33)
    __shared__ float logits_s[RPB * 104];
    __shared__ float coord_s[RPB * 4];
    __shared__ int   lb_s[RPB + 1];
    __shared__ float cnt_s[RPB];

    const int tid = threadIdx.x;
    const int R0  = blockIdx.x * RPB;

    if (tid <= RPB) {
        int v = R0 + tid;
        int lo = 0, hi = N;
        while (lo < hi) { int mid = (lo + hi) >> 1; if (batch[mid] < v) lo = mid + 1; else hi = mid; }
        lb_s[tid] = lo;
    }
    {   // stage t_emb rows R0..R0+3 -> half2 (one f4 per thread, coalesced)
        const float4* src = (const float4*)(t_emb + (size_t)R0 * HDIM);
        int r = tid >> 6, kq = tid & 63;
        float4 v = src[r * 64 + kq];
        H2U p0, p1;
        p0.h = (h2_t){(_Float16)v.x, (_Float16)v.y};
        p1.h = (h2_t){(_Float16)v.z, (_Float16)v.w};
        *(uint2*)&bufA[r * SH2 + kq * 2] = make_uint2(p0.u, p1.u);
    }
    __syncthreads();
    if (tid < RPB) cnt_s[tid] = (float)(lb_s[tid + 1] - lb_s[tid]);

    const int cg = tid & 31, j0 = cg * 4;
    const int ksg = tid >> 5;       // 8 K-groups x 16 k2
    const int wv  = tid >> 6;
    const bool lo_h = !(tid & 32);

    float acc[32];

    // ---------------- layer 1: h1 = silu(h0 @ w1a + b1a)   bufA -> bufB
#pragma unroll
    for (int i = 0; i < 32; ++i) acc[i] = 0.f;
    gemm_main_h(&bufA[ksg * 16], w1h + (size_t)(ksg * 16) * 256 + j0, acc);
    shfl_red<32>(acc);
    if (wv && lo_h) {
        float* rp = &red[(wv - 1) * 1056 + cg * 33];
#pragma unroll
        for (int i = 0; i < 32; ++i) rp[i] = acc[i];
    }
    __syncthreads();
    if (tid < 32) {
#pragma unroll
        for (int p = 0; p < 3; ++p) {
            const float* rp = &red[p * 1056 + tid * 33];
#pragma unroll
            for (int i = 0; i < 32; ++i) acc[i] += rp[i];
        }
        float4 bl = LD4(b1a + j0), bh = LD4(b1a + j0 + 128);
        const float bb_[8] = {bl.x, bl.y, bl.z, bl.w, bh.x, bh.y, bh.z, bh.w};
#pragma unroll
        for (int r = 0; r < 4; ++r) {
            float v[8];
#pragma unroll
            for (int c = 0; c < 8; ++c) v[c] = silu_f(acc[r * 8 + c] + bb_[c]);
            H2U p0, p1, p2, p3;
            p0.h = (h2_t){(_Float16)v[0], (_Float16)v[1]};
            p1.h = (h2_t){(_Float16)v[2], (_Float16)v[3]};
            p2.h = (h2_t){(_Float16)v[4], (_Float16)v[5]};
            p3.h = (h2_t){(_Float16)v[6], (_Float16)v[7]};
            *(uint2*)&bufB[r * SH2 + cg * 2]      = make_uint2(p0.u, p1.u);
            *(uint2*)&bufB[r * SH2 + 64 + cg * 2] = make_uint2(p2.u, p3.u);
        }
    }
    __syncthreads();

    // ---------------- layer 2: h = h1 @ w2a + b2a          bufB -> bufA
#pragma unroll
    for (int i = 0; i < 32; ++i) acc[i] = 0.f;
    gemm_main_h(&bufB[ksg * 16], w2h + (size_t)(ksg * 16) * 256 + j0, acc);
    shfl_red<32>(acc);
    if (wv && lo_h) {
        float* rp = &red[(wv - 1) * 1056 + cg * 33];
#pragma unroll
        for (int i = 0; i < 32; ++i) rp[i] = acc[i];
    }
    __syncthreads();
    if (tid < 32) {
#pragma unroll
        for (int p = 0; p < 3; ++p) {
            const float* rp = &red[p * 1056 + tid * 33];
#pragma unroll
            for (int i = 0; i < 32; ++i) acc[i] += rp[i];
        }
        float4 bl = LD4(b2a + j0), bh = LD4(b2a + j0 + 128);
        const float bb_[8] = {bl.x, bl.y, bl.z, bl.w, bh.x, bh.y, bh.z, bh.w};
#pragma unroll
        for (int r = 0; r < 4; ++r) {
            float v[8];
#pragma unroll
            for (int c = 0; c < 8; ++c) v[c] = acc[r * 8 + c] + bb_[c];
            H2U p0, p1, p2, p3;
            p0.h = (h2_t){(_Float16)v[0], (_Float16)v[1]};
            p1.h = (h2_t){(_Float16)v[2], (_Float16)v[3]};
            p2.h = (h2_t){(_Float16)v[4], (_Float16)v[5]};
            p3.h = (h2_t){(_Float16)v[6], (_Float16)v[7]};
            *(uint2*)&bufA[r * SH2 + cg * 2]      = make_uint2(p0.u, p1.u);
            *(uint2*)&bufA[r * SH2 + 64 + cg * 2] = make_uint2(p2.u, p3.u);
        }
    }
    __syncthreads();

    // ---------------- logits: h @ wt + bt -> logits_s (f32)
    {
        float la[16];
#pragma unroll
        for (int i = 0; i < 16; ++i) la[i] = 0.f;
        if (cg < 25)
            gemm_4x4h<16>(&bufA[ksg * 16], wth + (size_t)(ksg * 16) * 100 + j0, 100, la);
        shfl_red<16>(la);
        if (wv && lo_h && cg < 25) {
            float* rp = &red[(wv - 1) * 544 + cg * 17];
#pragma unroll
            for (int i = 0; i < 16; ++i) rp[i] = la[i];
        }
        __syncthreads();
        if (tid < 25) {
#pragma unroll
            for (int p = 0; p < 3; ++p) {
                const float* rp = &red[p * 544 + tid * 17];
#pragma unroll
                for (int i = 0; i < 16; ++i) la[i] += rp[i];
            }
            float4 b4 = LD4(bt + j0);
#pragma unroll
            for (int r = 0; r < 4; ++r)
                *(float4*)&logits_s[r * 104 + j0] =
                    make_float4(la[r*4+0] + b4.x, la[r*4+1] + b4.y,
                                la[r*4+2] + b4.z, la[r*4+3] + b4.w);
        }
        __syncthreads();
    }

    // -------- OVERLAP: waves 0-1 head hidden GEMMs || waves 2-3 stream logits
    if (tid < 128) {
        const bool ic  = (tid >= 64);           // wave0 coord, wave1 cell
        const int  hcg = tid & 31, hj0 = hcg * 4;
        const int  hks = (tid >> 5) & 1;        // K-half (64 k2)
        const unsigned* Wh = (ic ? wlh : wch) + (size_t)(hks * 64) * 128 + hj0;
        const float* bb2 = ic ? bl1 : bc1;
        float ha[16];
#pragma unroll
        for (int i = 0; i < 16; ++i) ha[i] = 0.f;
        gemm_4x4h<64>(&bufA[hks * 64], Wh, 128, ha);
        shfl_red<16>(ha);
        if (!(tid & 32)) {
            float4 b4 = LD4(bb2 + hj0);
            const int off2 = ic ? 64 : 0;
#pragma unroll
            for (int r = 0; r < 4; ++r) {
                // segment_sum == count*h; scale commutes through the dot
                const float sc = ic ? cnt_s[r] : 1.f;
                float v0 = silu_f(ha[r*4+0] * sc + b4.x);
                float v1 = silu_f(ha[r*4+1] * sc + b4.y);
                float v2 = silu_f(ha[r*4+2] * sc + b4.z);
                float v3 = silu_f(ha[r*4+3] * sc + b4.w);
                H2U p0, p1;
                p0.h = (h2_t){(_Float16)v0, (_Float16)v1};
                p1.h = (h2_t){(_Float16)v2, (_Float16)v3};
                *(uint2*)&bufB[r * SH2 + off2 + hcg * 2] = make_uint2(p0.u, p1.u);
            }
        }
    } else {
        const int st = tid - 128;               // 128 streaming threads
        const f32x4_n* ls4 = (const f32x4_n*)logits_s;   // row stride 26 f4
#pragma unroll 1
        for (int r = 0; r < RPB; ++r) {
            const int base = lb_s[r];
            const int tot  = (lb_s[r + 1] - base) * 25;
            const f32x4_n* lrow = ls4 + r * 26;
            for (int t = st; t < tot; t += 128) {
                unsigned a = (unsigned)t / 25u;
                unsigned q = (unsigned)t - a * 25u;
                f32x4_n v = lrow[q];
                __builtin_nontemporal_store(v, &out_logits4[(size_t)(base + a) * 25 + q]);
            }
        }
    }
    __syncthreads();

    // ---------------- tiny heads (read gc/gl half2)
    if (tid < 12) {
        int r = tid / 3, c = tid - 3 * r;
        float a = 0.f;
#pragma unroll 8
        for (int k2 = 0; k2 < 64; ++k2) {
            H2U u; u.u = bufB[r * SH2 + k2];
            a += (float)u.h.x * wc2[(2 * k2) * 3 + c]
               + (float)u.h.y * wc2[(2 * k2 + 1) * 3 + c];
        }
        coord_s[r * 4 + c] = a + bc2[c];
    } else if (tid < 36) {
        int t2 = tid - 12;
        int r = t2 / 6, c = t2 - 6 * r;
        float a = 0.f;
#pragma unroll 8
        for (int k2 = 0; k2 < 64; ++k2) {
            H2U u; u.u = bufB[r * SH2 + 64 + k2];
            a += (float)u.h.x * wl2[(2 * k2) * 6 + c]
               + (float)u.h.y * wl2[(2 * k2 + 1) * 6 + c];
        }
        cell_out[(size_t)(R0 + r) * 6 + c] = a + bl2[c];
    }
    __syncthreads();

    // ---------------- per-atom coord stream (6 MB, coalesced)
#pragma unroll 1
    for (int r = 0; r < RPB; ++r) {
        const int base = lb_s[r];
        const int tot3 = (lb_s[r + 1] - base) * 3;
        const float c0 = coord_s[r * 4 + 0];
        const float c1 = coord_s[r * 4 + 1];
        const float c2 = coord_s[r * 4 + 2];
        float* oc = out_coord + (size_t)base * 3;
        for (int t = tid; t < tot3; t += THREADS) {
            unsigned a = (unsigned)t / 3u;
            unsigned c = (unsigned)t - a * 3u;
            float v = (c == 0) ? c0 : (c == 1) ? c1 : c2;
            __builtin_nontemporal_store(v, &oc[t]);
        }
    }
}

extern "C" void kernel_launch(void* const* d_in, const int* in_sizes, int n_in,
                              void* d_out, int out_size, void* d_ws, size_t ws_size,
                              hipStream_t stream)
{
    const int*   batch = (const int*)d_in[1];
    const float* t_emb = (const float*)d_in[3];
    const float* w1a = (const float*)d_in[4];
    const float* b1a = (const float*)d_in[5];
    const float* w2a = (const float*)d_in[6];
    const float* b2a = (const float*)d_in[7];
    const float* wc1 = (const float*)d_in[8];
    const float* bc1 = (const float*)d_in[9];
    const float* wc2 = (const float*)d_in[10];
    const float* bc2 = (const float*)d_in[11];
    const float* wl1 = (const float*)d_in[12];
    const float* bl1 = (const float*)d_in[13];
    const float* wl2 = (const float*)d_in[14];
    const float* bl2 = (const float*)d_in[15];
    const float* wt  = (const float*)d_in[16];
    const float* bt  = (const float*)d_in[17];

    const int N = in_sizes[1];        // 500000
    const int B = in_sizes[2] / 9;    // 4096

    float* out        = (float*)d_out;
    float* out_coord  = out;                                   // [N,3]
    float* cell_out   = out + (size_t)N * 3;                   // [B,6]
    float* out_logits = out + (size_t)N * 3 + (size_t)B * 6;   // [N,100]

    unsigned* wpk = (unsigned*)d_ws;                           // 111104 uints

    convert_kernel<<<448, 256, 0, stream>>>(w1a, w2a, wt, wc1, wl1, wpk);

    fused_kernel<<<B / RPB, THREADS, 0, stream>>>(
        batch, N, t_emb, wpk,
        b1a, b2a, bc1, bl1,
        wc2, bc2, wl2, bl2, bt,
        out_coord, cell_out, (f32x4_n*)out_logits);
}